// Round 4
// baseline (488.789 us; speedup 1.0000x reference)
//
#include <hip/hip_runtime.h>
#include <math.h>
#include <stdint.h>

// FluxGNN1DLatent — MFMA formulation, round 4.
// out[b,n] = u[b,n]*S/(S+eps) - 0.5*(phi[n+1]-phi[n]),
//   phi[i] = 0.25/(S+eps) * sum_m enc[m]*tanh(f3[i][m]),
//   f3 = x2@W3+b3, x2 = gelu(x1@W2+b2), x1[i][k] = gelu(a_i*v1[k]+d_i*v2[k]+b1[k]).
// One wave = 64 interfaces (63 outputs); persistent waves over spans.
// Per nt-block (16 interfaces): layer2 MFMA (bias as C-in) -> gelu/pack ->
// 2KB wave-local transpose tile -> layer3 MFMA (bias as C-in) -> tanh/dot.
// phi neighbor via shfl_down; no sphi buffer; LDS ~9KB/block.

#define LD    32
#define HID   64
#define NN    65536
#define BB    32
#define SPANS 1041                 // ceil(65536/63)
#define WPB   4
#define GRID  2048
#define TOTAL_SPANS (BB * SPANS)   // 33312

typedef __attribute__((ext_vector_type(8))) short bf16x8;
typedef __attribute__((ext_vector_type(4))) float f32x4;
typedef __attribute__((ext_vector_type(2))) float v2f;
typedef __attribute__((ext_vector_type(4))) unsigned int u32x4;

__device__ __forceinline__ uint32_t cvt_pk_bf16(float lo, float hi) {
    uint32_t r;
    asm("v_cvt_pk_bf16_f32 %0, %1, %2" : "=v"(r) : "v"(lo), "v"(hi));
    return r;
}

// gelu(x) = x*(1 - 1/(exp2(C1*x + C3*x^3) + 1)); C1=2*log2e*0.7978845608
__device__ __forceinline__ v2f gelu2(v2f x) {
    const v2f xx    = x * x;
    const v2f inner = xx * 0.10294322f + 2.3022077f;
    const v2f arg   = x * inner;
    v2f t;
    t.x = __builtin_amdgcn_exp2f(arg.x);
    t.y = __builtin_amdgcn_exp2f(arg.y);
    const v2f d = t + 1.0f;
    v2f r;
    r.x = __builtin_amdgcn_rcpf(d.x);
    r.y = __builtin_amdgcn_rcpf(d.y);
    return x - x * r;
}

// tanh(y) = 1 - 2/(exp2(2*log2e*y)+1)
__device__ __forceinline__ v2f tanh2(v2f y) {
    const v2f a = y * 2.8853901f;
    v2f t;
    t.x = __builtin_amdgcn_exp2f(a.x);
    t.y = __builtin_amdgcn_exp2f(a.y);
    const v2f d = t + 1.0f;
    v2f r;
    r.x = __builtin_amdgcn_rcpf(d.x);
    r.y = __builtin_amdgcn_rcpf(d.y);
    return 1.0f - 2.0f * r;
}

__global__ __launch_bounds__(256, 4)
void fluxgnn_mfma(const float* __restrict__ u,  const float* __restrict__ enc,
                  const float* __restrict__ W1, const float* __restrict__ b1,
                  const float* __restrict__ W2, const float* __restrict__ b2,
                  const float* __restrict__ W3, const float* __restrict__ b3,
                  float* __restrict__ out)
{
    __shared__ __align__(16) short xT[WPB][16][64];   // 2KB per wave, reused per nt
    __shared__ __align__(16) float sv1[HID];
    __shared__ __align__(16) float sv2[HID];

    const int tid = threadIdx.x;
    const int w   = tid >> 6;
    const int l   = tid & 63;
    const int c   = l & 15;
    const int g   = l >> 4;

    // ---- block-cooperative: v1[j] = enc.W1[0:32,j], v2[j] = |enc|.W1[32:64,j]
    if (tid < HID) {
        float a1 = 0.f, a2 = 0.f;
        #pragma unroll
        for (int m = 0; m < LD; ++m) {
            const float e = enc[m];
            a1 = fmaf(e,        W1[m * HID + tid],        a1);
            a2 = fmaf(fabsf(e), W1[(LD + m) * HID + tid], a2);
        }
        sv1[tid] = a1;
        sv2[tid] = a2;
    }

    float S = 0.f;
    #pragma unroll
    for (int m = 0; m < LD; ++m) { const float e = enc[m]; S = fmaf(e, e, S); }
    const float inv  = 1.0f / (S + 1e-12f);
    const float selt = S * inv;

    // ---- per-wave constant fragments (once, amortized over spans)
    bf16x8 a2f[4][2];           // W2^T: A[m=16mt+c][k=32kt+8g+j]
    #pragma unroll
    for (int mt = 0; mt < 4; ++mt)
        #pragma unroll
        for (int kt = 0; kt < 2; ++kt) {
            u32x4 uu;
            #pragma unroll
            for (int p = 0; p < 4; ++p) {
                const int k0 = 32*kt + 8*g + 2*p;
                uu[p] = cvt_pk_bf16(W2[k0 * HID + 16*mt + c],
                                    W2[(k0 + 1) * HID + 16*mt + c]);
            }
            a2f[mt][kt] = __builtin_bit_cast(bf16x8, uu);
        }

    bf16x8 a3f[2][2];           // W3^T: A[m=16mt+c][k=32kt+8g+j]
    #pragma unroll
    for (int mt = 0; mt < 2; ++mt)
        #pragma unroll
        for (int kt = 0; kt < 2; ++kt) {
            u32x4 uu;
            #pragma unroll
            for (int p = 0; p < 4; ++p) {
                const int k0 = 32*kt + 8*g + 2*p;
                uu[p] = cvt_pk_bf16(W3[k0 * LD + 16*mt + c],
                                    W3[(k0 + 1) * LD + 16*mt + c]);
            }
            a3f[mt][kt] = __builtin_bit_cast(bf16x8, uu);
        }

    // biases as MFMA C-in vectors: C[row=4g+q][col] = b[16mt+4g+q]
    f32x4 b2q[4], b3q[2];
    #pragma unroll
    for (int mt = 0; mt < 4; ++mt)
        b2q[mt] = *reinterpret_cast<const f32x4*>(b2 + 16*mt + 4*g);
    #pragma unroll
    for (int mt = 0; mt < 2; ++mt)
        b3q[mt] = *reinterpret_cast<const f32x4*>(b3 + 16*mt + 4*g);

    // enc pairs scaled by 0.25*inv (folds the phi scale)
    const v2f* encv = (const v2f*)enc;
    v2f encp[2][2];
    #pragma unroll
    for (int mt = 0; mt < 2; ++mt) {
        encp[mt][0] = encv[8*mt + 2*g + 0] * (0.25f * inv);
        encp[mt][1] = encv[8*mt + 2*g + 1] * (0.25f * inv);
    }

    __syncthreads();

    // per-lane layer-1 coefficient pairs at k = 32kt + 8g + 2p (+1)
    const v2f* sv1v = (const v2f*)sv1;
    const v2f* sv2v = (const v2f*)sv2;
    const v2f* b1v  = (const v2f*)b1;
    v2f v1p[2][4], v2p[2][4], b1p[2][4];
    #pragma unroll
    for (int kt = 0; kt < 2; ++kt)
        #pragma unroll
        for (int p = 0; p < 4; ++p) {
            const int idx = 16*kt + 4*g + p;
            v1p[kt][p] = sv1v[idx];
            v2p[kt][p] = sv2v[idx];
            b1p[kt][p] = b1v[idx];
        }

    short* const xbase = &xT[w][0][0];
    const int swz    = (c & 7) << 1;
    const int rowoff = c * 64;

    // ---- persistent span loop
    for (int sid = blockIdx.x * WPB + w; sid < TOTAL_SPANS; sid += GRID * WPB) {
        const int row  = sid / SPANS;
        const int span = sid - row * SPANS;
        const int n0   = span * 63;
        const float* __restrict__ urow = u + row * NN;

        // u features for this lane's 4 interfaces (i = n0 + 16*nt + c)
        float af[4], df[4];
        #pragma unroll
        for (int nt = 0; nt < 4; ++nt) {
            const int i = n0 + 16*nt + c;
            int il = i - 1; il = il < 0 ? 0 : (il > NN-1 ? NN-1 : il);
            const int ir = i > NN-1 ? NN-1 : i;
            const float ul = urow[il], ur = urow[ir];
            af[nt] = ul + ur;
            df[nt] = fabsf(ur - ul);
        }

        float phi_[4];
        #pragma unroll
        for (int nt = 0; nt < 4; ++nt) {
            const v2f av = { af[nt], af[nt] };
            const v2f dv = { df[nt], df[nt] };

            // ---- layer 1+2 (swapped): C2[h2][i], bias as C-in at kt==0
            f32x4 acc[4];
            #pragma unroll
            for (int kt = 0; kt < 2; ++kt) {
                u32x4 uu;
                #pragma unroll
                for (int p = 0; p < 4; ++p) {
                    const v2f pre = av * v1p[kt][p] + (dv * v2p[kt][p] + b1p[kt][p]);
                    const v2f gg  = gelu2(pre);
                    uu[p] = cvt_pk_bf16(gg.x, gg.y);
                }
                const bf16x8 bfrag = __builtin_bit_cast(bf16x8, uu);
                #pragma unroll
                for (int mt = 0; mt < 4; ++mt)
                    acc[mt] = __builtin_amdgcn_mfma_f32_16x16x32_bf16(
                                  a2f[mt][kt], bfrag, kt == 0 ? b2q[mt] : acc[mt],
                                  0, 0, 0);
            }

            // ---- gelu, pack, transpose-store into the 16x64 tile (swizzled)
            #pragma unroll
            for (int mt = 0; mt < 4; ++mt) {
                const v2f y01 = gelu2((v2f){acc[mt][0], acc[mt][1]});
                const v2f y23 = gelu2((v2f){acc[mt][2], acc[mt][3]});
                uint2 pk;
                pk.x = cvt_pk_bf16(y01.x, y01.y);
                pk.y = cvt_pk_bf16(y23.x, y23.y);
                const int cs = (4*mt + g) ^ swz;
                *reinterpret_cast<uint2*>(xbase + rowoff + cs*4) = pk;
            }

            // ---- layer 3 (swapped): C3[ld][i] for this nt, bias as C-in
            f32x4 a3acc[2];
            #pragma unroll
            for (int kt = 0; kt < 2; ++kt) {
                const int p = (8*kt + 2*g) ^ swz;   // even -> 16B aligned
                const bf16x8 bfr =
                    *reinterpret_cast<const bf16x8*>(xbase + rowoff + p*4);
                #pragma unroll
                for (int mt = 0; mt < 2; ++mt)
                    a3acc[mt] = __builtin_amdgcn_mfma_f32_16x16x32_bf16(
                                    a3f[mt][kt], bfr, kt == 0 ? b3q[mt] : a3acc[mt],
                                    0, 0, 0);
            }

            // ---- tanh + scaled-enc dot + g-group reduction -> phi
            v2f sacc = {0.f, 0.f};
            #pragma unroll
            for (int mt = 0; mt < 2; ++mt) {
                sacc += tanh2((v2f){a3acc[mt][0], a3acc[mt][1]}) * encp[mt][0];
                sacc += tanh2((v2f){a3acc[mt][2], a3acc[mt][3]}) * encp[mt][1];
            }
            float s = sacc.x + sacc.y;
            s += __shfl_xor(s, 16);
            s += __shfl_xor(s, 32);
            phi_[nt] = s;
        }

        float myphi = phi_[0];
        if (g == 1) myphi = phi_[1];
        if (g == 2) myphi = phi_[2];
        if (g == 3) myphi = phi_[3];
        const float pn1 = __shfl_down(myphi, 1);

        // ---- outputs n = n0 + l, l < 63
        if (l < 63) {
            const int n = n0 + l;
            if (n < NN) {
                out[row * NN + n] = fmaf(urow[n], selt, -0.5f * (pn1 - myphi));
            }
        }
    }
}

extern "C" void kernel_launch(void* const* d_in, const int* in_sizes, int n_in,
                              void* d_out, int out_size, void* d_ws, size_t ws_size,
                              hipStream_t stream) {
    const float* u   = (const float*)d_in[0];
    const float* enc = (const float*)d_in[1];
    const float* W1  = (const float*)d_in[2];
    const float* b1  = (const float*)d_in[3];
    const float* W2  = (const float*)d_in[4];
    const float* b2  = (const float*)d_in[5];
    const float* W3  = (const float*)d_in[6];
    const float* b3  = (const float*)d_in[7];
    float* out = (float*)d_out;

    fluxgnn_mfma<<<GRID, 64 * WPB, 0, stream>>>(u, enc, W1, b1, W2, b2, W3, b3, out);
}

// Round 5
// 110.332 us; speedup vs baseline: 4.4301x; 4.4301x over previous
//
#include <hip/hip_runtime.h>
#include <math.h>
#include <stdint.h>

// FluxGNN1DLatent — MFMA formulation, round 5.
// Identical structure to round 4 (bias-as-C-in, 2KB per-wave transpose tile,
// shfl-based phi neighbor) but launch bounds back to (256,2): round 4's
// (256,4) capped VGPRs at 128 and spilled ~150 regs of persistent wave state
// to scratch (FETCH 1.36GB, WRITE 412MB — pure spill traffic).

#define LD    32
#define HID   64
#define NN    65536
#define BB    32
#define SPANS 1041                 // ceil(65536/63)
#define WPB   4
#define GRID  2048
#define TOTAL_SPANS (BB * SPANS)   // 33312

typedef __attribute__((ext_vector_type(8))) short bf16x8;
typedef __attribute__((ext_vector_type(4))) float f32x4;
typedef __attribute__((ext_vector_type(2))) float v2f;
typedef __attribute__((ext_vector_type(4))) unsigned int u32x4;

__device__ __forceinline__ uint32_t cvt_pk_bf16(float lo, float hi) {
    uint32_t r;
    asm("v_cvt_pk_bf16_f32 %0, %1, %2" : "=v"(r) : "v"(lo), "v"(hi));
    return r;
}

// gelu(x) = x*(1 - 1/(exp2(C1*x + C3*x^3) + 1)); C1=2*log2e*0.7978845608
__device__ __forceinline__ v2f gelu2(v2f x) {
    const v2f xx    = x * x;
    const v2f inner = xx * 0.10294322f + 2.3022077f;
    const v2f arg   = x * inner;
    v2f t;
    t.x = __builtin_amdgcn_exp2f(arg.x);
    t.y = __builtin_amdgcn_exp2f(arg.y);
    const v2f d = t + 1.0f;
    v2f r;
    r.x = __builtin_amdgcn_rcpf(d.x);
    r.y = __builtin_amdgcn_rcpf(d.y);
    return x - x * r;
}

// tanh(y) = 1 - 2/(exp2(2*log2e*y)+1)
__device__ __forceinline__ v2f tanh2(v2f y) {
    const v2f a = y * 2.8853901f;
    v2f t;
    t.x = __builtin_amdgcn_exp2f(a.x);
    t.y = __builtin_amdgcn_exp2f(a.y);
    const v2f d = t + 1.0f;
    v2f r;
    r.x = __builtin_amdgcn_rcpf(d.x);
    r.y = __builtin_amdgcn_rcpf(d.y);
    return 1.0f - 2.0f * r;
}

__global__ __launch_bounds__(256, 2)
void fluxgnn_mfma(const float* __restrict__ u,  const float* __restrict__ enc,
                  const float* __restrict__ W1, const float* __restrict__ b1,
                  const float* __restrict__ W2, const float* __restrict__ b2,
                  const float* __restrict__ W3, const float* __restrict__ b3,
                  float* __restrict__ out)
{
    __shared__ __align__(16) short xT[WPB][16][64];   // 2KB per wave, reused per nt
    __shared__ __align__(16) float sv1[HID];
    __shared__ __align__(16) float sv2[HID];

    const int tid = threadIdx.x;
    const int w   = tid >> 6;
    const int l   = tid & 63;
    const int c   = l & 15;
    const int g   = l >> 4;

    // ---- block-cooperative: v1[j] = enc.W1[0:32,j], v2[j] = |enc|.W1[32:64,j]
    if (tid < HID) {
        float a1 = 0.f, a2 = 0.f;
        #pragma unroll
        for (int m = 0; m < LD; ++m) {
            const float e = enc[m];
            a1 = fmaf(e,        W1[m * HID + tid],        a1);
            a2 = fmaf(fabsf(e), W1[(LD + m) * HID + tid], a2);
        }
        sv1[tid] = a1;
        sv2[tid] = a2;
    }

    float S = 0.f;
    #pragma unroll
    for (int m = 0; m < LD; ++m) { const float e = enc[m]; S = fmaf(e, e, S); }
    const float inv  = 1.0f / (S + 1e-12f);
    const float selt = S * inv;

    // ---- per-wave constant fragments (once, amortized over spans)
    bf16x8 a2f[4][2];           // W2^T: A[m=16mt+c][k=32kt+8g+j]
    #pragma unroll
    for (int mt = 0; mt < 4; ++mt)
        #pragma unroll
        for (int kt = 0; kt < 2; ++kt) {
            u32x4 uu;
            #pragma unroll
            for (int p = 0; p < 4; ++p) {
                const int k0 = 32*kt + 8*g + 2*p;
                uu[p] = cvt_pk_bf16(W2[k0 * HID + 16*mt + c],
                                    W2[(k0 + 1) * HID + 16*mt + c]);
            }
            a2f[mt][kt] = __builtin_bit_cast(bf16x8, uu);
        }

    bf16x8 a3f[2][2];           // W3^T: A[m=16mt+c][k=32kt+8g+j]
    #pragma unroll
    for (int mt = 0; mt < 2; ++mt)
        #pragma unroll
        for (int kt = 0; kt < 2; ++kt) {
            u32x4 uu;
            #pragma unroll
            for (int p = 0; p < 4; ++p) {
                const int k0 = 32*kt + 8*g + 2*p;
                uu[p] = cvt_pk_bf16(W3[k0 * LD + 16*mt + c],
                                    W3[(k0 + 1) * LD + 16*mt + c]);
            }
            a3f[mt][kt] = __builtin_bit_cast(bf16x8, uu);
        }

    // biases as MFMA C-in vectors: C[row=4g+q][col] = b[16mt+4g+q]
    f32x4 b2q[4], b3q[2];
    #pragma unroll
    for (int mt = 0; mt < 4; ++mt)
        b2q[mt] = *reinterpret_cast<const f32x4*>(b2 + 16*mt + 4*g);
    #pragma unroll
    for (int mt = 0; mt < 2; ++mt)
        b3q[mt] = *reinterpret_cast<const f32x4*>(b3 + 16*mt + 4*g);

    // enc pairs scaled by 0.25*inv (folds the phi scale)
    const v2f* encv = (const v2f*)enc;
    v2f encp[2][2];
    #pragma unroll
    for (int mt = 0; mt < 2; ++mt) {
        encp[mt][0] = encv[8*mt + 2*g + 0] * (0.25f * inv);
        encp[mt][1] = encv[8*mt + 2*g + 1] * (0.25f * inv);
    }

    __syncthreads();

    // per-lane layer-1 coefficient pairs at k = 32kt + 8g + 2p (+1)
    const v2f* sv1v = (const v2f*)sv1;
    const v2f* sv2v = (const v2f*)sv2;
    const v2f* b1v  = (const v2f*)b1;
    v2f v1p[2][4], v2p[2][4], b1p[2][4];
    #pragma unroll
    for (int kt = 0; kt < 2; ++kt)
        #pragma unroll
        for (int p = 0; p < 4; ++p) {
            const int idx = 16*kt + 4*g + p;
            v1p[kt][p] = sv1v[idx];
            v2p[kt][p] = sv2v[idx];
            b1p[kt][p] = b1v[idx];
        }

    short* const xbase = &xT[w][0][0];
    const int swz    = (c & 7) << 1;
    const int rowoff = c * 64;

    // ---- persistent span loop
    for (int sid = blockIdx.x * WPB + w; sid < TOTAL_SPANS; sid += GRID * WPB) {
        const int row  = sid / SPANS;
        const int span = sid - row * SPANS;
        const int n0   = span * 63;
        const float* __restrict__ urow = u + row * NN;

        // u features for this lane's 4 interfaces (i = n0 + 16*nt + c)
        float af[4], df[4];
        #pragma unroll
        for (int nt = 0; nt < 4; ++nt) {
            const int i = n0 + 16*nt + c;
            int il = i - 1; il = il < 0 ? 0 : (il > NN-1 ? NN-1 : il);
            const int ir = i > NN-1 ? NN-1 : i;
            const float ul = urow[il], ur = urow[ir];
            af[nt] = ul + ur;
            df[nt] = fabsf(ur - ul);
        }

        float phi_[4];
        #pragma unroll
        for (int nt = 0; nt < 4; ++nt) {
            const v2f av = { af[nt], af[nt] };
            const v2f dv = { df[nt], df[nt] };

            // ---- layer 1+2 (swapped): C2[h2][i], bias as C-in at kt==0
            f32x4 acc[4];
            #pragma unroll
            for (int kt = 0; kt < 2; ++kt) {
                u32x4 uu;
                #pragma unroll
                for (int p = 0; p < 4; ++p) {
                    const v2f pre = av * v1p[kt][p] + (dv * v2p[kt][p] + b1p[kt][p]);
                    const v2f gg  = gelu2(pre);
                    uu[p] = cvt_pk_bf16(gg.x, gg.y);
                }
                const bf16x8 bfrag = __builtin_bit_cast(bf16x8, uu);
                #pragma unroll
                for (int mt = 0; mt < 4; ++mt)
                    acc[mt] = __builtin_amdgcn_mfma_f32_16x16x32_bf16(
                                  a2f[mt][kt], bfrag, kt == 0 ? b2q[mt] : acc[mt],
                                  0, 0, 0);
            }

            // ---- gelu, pack, transpose-store into the 16x64 tile (swizzled)
            #pragma unroll
            for (int mt = 0; mt < 4; ++mt) {
                const v2f y01 = gelu2((v2f){acc[mt][0], acc[mt][1]});
                const v2f y23 = gelu2((v2f){acc[mt][2], acc[mt][3]});
                uint2 pk;
                pk.x = cvt_pk_bf16(y01.x, y01.y);
                pk.y = cvt_pk_bf16(y23.x, y23.y);
                const int cs = (4*mt + g) ^ swz;
                *reinterpret_cast<uint2*>(xbase + rowoff + cs*4) = pk;
            }

            // ---- layer 3 (swapped): C3[ld][i] for this nt, bias as C-in
            f32x4 a3acc[2];
            #pragma unroll
            for (int kt = 0; kt < 2; ++kt) {
                const int p = (8*kt + 2*g) ^ swz;   // even -> 16B aligned
                const bf16x8 bfr =
                    *reinterpret_cast<const bf16x8*>(xbase + rowoff + p*4);
                #pragma unroll
                for (int mt = 0; mt < 2; ++mt)
                    a3acc[mt] = __builtin_amdgcn_mfma_f32_16x16x32_bf16(
                                    a3f[mt][kt], bfr, kt == 0 ? b3q[mt] : a3acc[mt],
                                    0, 0, 0);
            }

            // ---- tanh + scaled-enc dot + g-group reduction -> phi
            v2f sacc = {0.f, 0.f};
            #pragma unroll
            for (int mt = 0; mt < 2; ++mt) {
                sacc += tanh2((v2f){a3acc[mt][0], a3acc[mt][1]}) * encp[mt][0];
                sacc += tanh2((v2f){a3acc[mt][2], a3acc[mt][3]}) * encp[mt][1];
            }
            float s = sacc.x + sacc.y;
            s += __shfl_xor(s, 16);
            s += __shfl_xor(s, 32);
            phi_[nt] = s;
        }

        float myphi = phi_[0];
        if (g == 1) myphi = phi_[1];
        if (g == 2) myphi = phi_[2];
        if (g == 3) myphi = phi_[3];
        const float pn1 = __shfl_down(myphi, 1);

        // ---- outputs n = n0 + l, l < 63
        if (l < 63) {
            const int n = n0 + l;
            if (n < NN) {
                out[row * NN + n] = fmaf(urow[n], selt, -0.5f * (pn1 - myphi));
            }
        }
    }
}

extern "C" void kernel_launch(void* const* d_in, const int* in_sizes, int n_in,
                              void* d_out, int out_size, void* d_ws, size_t ws_size,
                              hipStream_t stream) {
    const float* u   = (const float*)d_in[0];
    const float* enc = (const float*)d_in[1];
    const float* W1  = (const float*)d_in[2];
    const float* b1  = (const float*)d_in[3];
    const float* W2  = (const float*)d_in[4];
    const float* b2  = (const float*)d_in[5];
    const float* W3  = (const float*)d_in[6];
    const float* b3  = (const float*)d_in[7];
    float* out = (float*)d_out;

    fluxgnn_mfma<<<GRID, 64 * WPB, 0, stream>>>(u, enc, W1, b1, W2, b2, W3, b3, out);
}